// Round 4
// baseline (395.391 us; speedup 1.0000x reference)
//
#include <hip/hip_runtime.h>
#include <hip/hip_bf16.h>
#include <math.h>

#define NE 8
#define KDG 1024
#define KDI 1024
#define NHG 512
#define NH 2048
#define NC 512
#define NB 4096

typedef float f32x4 __attribute__((ext_vector_type(4)));
typedef short s16x8 __attribute__((ext_vector_type(8)));
typedef short s16x4 __attribute__((ext_vector_type(4)));

__device__ __forceinline__ void gld_lds16(const void* g, void* l){
  __builtin_amdgcn_global_load_lds((const __attribute__((address_space(1))) void*)g,
                                   (__attribute__((address_space(3))) void*)l, 16, 0, 0);
}

// ---------------- split x into hi/lo bf16 ----------------
__global__ void k_split_x(const float* __restrict__ in, __hip_bfloat16* __restrict__ oh,
                          __hip_bfloat16* __restrict__ ol){
  size_t i = ((size_t)blockIdx.x*256 + threadIdx.x)*4;
  f32x4 v = *reinterpret_cast<const f32x4*>(in + i);
  union { __hip_bfloat16 h[4]; s16x4 s; } uh, ul;
  #pragma unroll
  for (int j=0;j<4;j++){
    uh.h[j] = __float2bfloat16(v[j]);
    ul.h[j] = __float2bfloat16(v[j] - __bfloat162float(uh.h[j]));
  }
  *reinterpret_cast<s16x4*>(oh + i) = uh.s;
  *reinterpret_cast<s16x4*>(ol + i) = ul.s;
}

// ---------------- transpose + hi/lo split Wg1 [R][C] -> [C][R] ----------------
__global__ __launch_bounds__(256) void k_split_wt(const float* __restrict__ W,
                                                  __hip_bfloat16* __restrict__ Wth,
                                                  __hip_bfloat16* __restrict__ Wtl){
  __shared__ float tile[64][65];
  const int r0 = blockIdx.y*64, c0 = blockIdx.x*64;
  const int t = threadIdx.x;
  const int tx = t & 15, ty = t >> 4;
  #pragma unroll
  for (int p=0;p<4;p++){
    f32x4 v = *reinterpret_cast<const f32x4*>(&W[(size_t)(r0+ty+p*16)*NHG + c0 + tx*4]);
    #pragma unroll
    for (int j=0;j<4;j++) tile[ty+p*16][tx*4+j] = v[j];
  }
  __syncthreads();
  const int cx = t & 7, cy = t >> 3;
  #pragma unroll
  for (int p=0;p<2;p++){
    int c = cy + p*32;
    union { __hip_bfloat16 h[8]; s16x8 s; } uh, ul;
    #pragma unroll
    for (int j=0;j<8;j++){
      float v = tile[cx*8+j][c];
      uh.h[j] = __float2bfloat16(v);
      ul.h[j] = __float2bfloat16(v - __bfloat162float(uh.h[j]));
    }
    *reinterpret_cast<s16x8*>(&Wth[(size_t)(c0+c)*KDG + r0 + cx*8]) = uh.s;
    *reinterpret_cast<s16x8*>(&Wtl[(size_t)(c0+c)*KDG + r0 + cx*8]) = ul.s;
  }
}

// ---------------- gating GEMM1 via hi/lo bf16 MFMA, 128x64 tile ----------------
__global__ __launch_bounds__(256) void k_gate_mm(const __hip_bfloat16* __restrict__ xh,
                                                 const __hip_bfloat16* __restrict__ xl,
                                                 const __hip_bfloat16* __restrict__ wh,
                                                 const __hip_bfloat16* __restrict__ wl,
                                                 const float* __restrict__ bg1,
                                                 float* __restrict__ hg){
  __shared__ __hip_bfloat16 Ah[2][128][32] __attribute__((aligned(16)));
  __shared__ __hip_bfloat16 Ax[2][128][32] __attribute__((aligned(16)));
  __shared__ __hip_bfloat16 Bh[2][64][32]  __attribute__((aligned(16)));
  __shared__ __hip_bfloat16 Bx[2][64][32]  __attribute__((aligned(16)));
  const int m0 = blockIdx.y*128, n0 = blockIdx.x*64;
  const int t = threadIdx.x, lane = t&63, wid = t>>6;
  const int rr = t>>2, kq = t&3;
  const __hip_bfloat16* pah = xh + (size_t)(m0+rr)*KDG + kq*8;
  const __hip_bfloat16* pax = xl + (size_t)(m0+rr)*KDG + kq*8;
  const __hip_bfloat16* pbh = wh + (size_t)(n0+rr)*KDG + kq*8;
  const __hip_bfloat16* pbx = wl + (size_t)(n0+rr)*KDG + kq*8;

  const int wm = wid>>1, wn = wid&1;    // wave covers m: wm*64..+64, n: wn*32..+32
  f32x4 acc[4][2];
  #pragma unroll
  for (int i=0;i<4;i++)
    #pragma unroll
    for (int j=0;j<2;j++){ f32x4 z={0.f,0.f,0.f,0.f}; acc[i][j]=z; }

  auto stage = [&](int buf, int k0){
    size_t wo = (size_t)(wid<<10);
    gld_lds16(pah + k0,            (char*)(&Ah[buf][0][0]) + wo);
    gld_lds16(pah + 64*KDG + k0,   (char*)(&Ah[buf][0][0]) + wo + 4096);
    gld_lds16(pax + k0,            (char*)(&Ax[buf][0][0]) + wo);
    gld_lds16(pax + 64*KDG + k0,   (char*)(&Ax[buf][0][0]) + wo + 4096);
    gld_lds16(pbh + k0,            (char*)(&Bh[buf][0][0]) + wo);
    gld_lds16(pbx + k0,            (char*)(&Bx[buf][0][0]) + wo);
  };

  stage(0, 0);
  __syncthreads();
  for (int ks=0; ks<KDG/32; ++ks){
    const int buf = ks & 1;
    if (ks+1 < KDG/32) stage(buf^1, (ks+1)*32);
    const int rb = lane&15, kb = (lane>>4)*8;
    s16x8 ah[4], ax[4], bh[2], bx[2];
    #pragma unroll
    for (int mi=0;mi<4;mi++){
      ah[mi] = *reinterpret_cast<const s16x8*>(&Ah[buf][wm*64+mi*16+rb][kb]);
      ax[mi] = *reinterpret_cast<const s16x8*>(&Ax[buf][wm*64+mi*16+rb][kb]);
    }
    #pragma unroll
    for (int ni=0;ni<2;ni++){
      bh[ni] = *reinterpret_cast<const s16x8*>(&Bh[buf][wn*32+ni*16+rb][kb]);
      bx[ni] = *reinterpret_cast<const s16x8*>(&Bx[buf][wn*32+ni*16+rb][kb]);
    }
    #pragma unroll
    for (int mi=0;mi<4;mi++)
      #pragma unroll
      for (int ni=0;ni<2;ni++){
        acc[mi][ni] = __builtin_amdgcn_mfma_f32_16x16x32_bf16(ah[mi], bh[ni], acc[mi][ni], 0,0,0);
        acc[mi][ni] = __builtin_amdgcn_mfma_f32_16x16x32_bf16(ah[mi], bx[ni], acc[mi][ni], 0,0,0);
        acc[mi][ni] = __builtin_amdgcn_mfma_f32_16x16x32_bf16(ax[mi], bh[ni], acc[mi][ni], 0,0,0);
      }
    __syncthreads();
  }
  const int rb = lane&15;
  #pragma unroll
  for (int mi=0;mi<4;mi++){
    #pragma unroll
    for (int j=0;j<4;j++){
      int row = m0 + wm*64 + mi*16 + (lane>>4)*4 + j;
      #pragma unroll
      for (int ni=0;ni<2;ni++){
        int col = n0 + wn*32 + ni*16 + rb;
        hg[(size_t)row*NHG + col] = fmaxf(acc[mi][ni][j] + bg1[col], 0.f);
      }
    }
  }
}

// ---------------- top-2 per token: logits, gates (NO atomics) ----------------
__global__ __launch_bounds__(256) void k_topk(const float* __restrict__ hg,
                                              const float* __restrict__ Wg2,
                                              const float* __restrict__ bg2,
                                              int* __restrict__ tok_e,
                                              float* __restrict__ tok_gate){
  __shared__ float w[NE][NHG];
  const int t = threadIdx.x;
  for (int i=t; i<NE*NHG; i+=256){ int k=i>>3, e=i&7; w[e][k] = Wg2[i]; }
  __syncthreads();
  const int lane = t & 63, wid = t >> 6;
  const int b = blockIdx.x*4 + wid;
  float acc[NE];
  #pragma unroll
  for (int e=0;e<NE;e++) acc[e]=0.f;
  #pragma unroll
  for (int j=0;j<8;j++){
    float hv = hg[(size_t)b*NHG + j*64 + lane];
    #pragma unroll
    for (int e=0;e<NE;e++) acc[e] += hv * w[e][j*64+lane];
  }
  #pragma unroll
  for (int e=0;e<NE;e++){
    float v = acc[e];
    #pragma unroll
    for (int s=32;s;s>>=1) v += __shfl_xor(v, s, 64);
    acc[e] = v;
  }
  if (lane==0){
    float lg[NE];
    #pragma unroll
    for (int e=0;e<NE;e++) lg[e] = acc[e] + bg2[e];
    int i1=0;
    #pragma unroll
    for (int e=1;e<NE;e++) if (lg[e] > lg[i1]) i1=e;
    int i2 = (i1==0)?1:0;
    #pragma unroll
    for (int e=0;e<NE;e++){ if (e==i1 || e==i2) continue; if (lg[e] > lg[i2]) i2=e; }
    float pr = expf((lg[i2]-lg[i1])*0.2f);
    float s  = 1.f + pr;
    tok_e[b*2]=i1;      tok_e[b*2+1]=i2;
    tok_gate[b*2]=1.f/s; tok_gate[b*2+1]=pr/s;
  }
}

// ---------------- dispatcher build: ONE block, LDS atomics only ----------------
__global__ __launch_bounds__(1024) void k_dispatch(const int* __restrict__ tok_e,
                                                   const float* __restrict__ tok_gate,
                                                   int* __restrict__ cnt, int* __restrict__ offs,
                                                   int* __restrict__ tlist, int* __restrict__ tok_row,
                                                   float* __restrict__ loss_out){
  __shared__ int lcnt[NE];
  __shared__ float limp[NE];
  __shared__ int loffs[NE];
  const int t = threadIdx.x;
  if (t < NE){ lcnt[t]=0; limp[t]=0.f; }
  __syncthreads();
  int e[8], p[8];
  #pragma unroll
  for (int j=0;j<8;j++){
    int i = t*8+j;
    e[j] = tok_e[i];
    p[j] = atomicAdd(&lcnt[e[j]], 1);
    atomicAdd(&limp[e[j]], tok_gate[i]);
  }
  __syncthreads();
  if (t==0){
    int o=0; float si=0.f, sl=0.f;
    for (int k=0;k<NE;k++){ loffs[k]=o; o+=lcnt[k]; si+=limp[k]; sl+=(float)lcnt[k]; }
    float mi=si/NE, ml=sl/NE, vi=0.f, vl=0.f;
    for (int k=0;k<NE;k++){ float d=limp[k]-mi; vi+=d*d; float dl=(float)lcnt[k]-ml; vl+=dl*dl; }
    vi/=(NE-1); vl/=(NE-1);
    loss_out[0] = (vi/(mi*mi+1e-10f) + vl/(ml*ml+1e-10f)) * 0.01f;
  }
  __syncthreads();
  if (t < NE){ cnt[t]=lcnt[t]; offs[t]=loffs[t]; }
  #pragma unroll
  for (int j=0;j<8;j++){
    int i = t*8+j;
    int row = loffs[e[j]] + p[j];
    tok_row[i] = row;
    tlist[row] = i>>1;
  }
}

// ---------------- pack: gather x2 rows by assignment order + convert to bf16 ----------------
__global__ __launch_bounds__(256) void k_pack(const float* __restrict__ x2,
                                              const int* __restrict__ tlist,
                                              __hip_bfloat16* __restrict__ Ap){
  const int r = blockIdx.x*2 + (threadIdx.x>>7);   // packed row
  const int c = threadIdx.x & 127;
  const int src = tlist[r];
  const float* s = x2 + (size_t)src*KDI;
  __hip_bfloat16* d = Ap + (size_t)r*KDI;
  #pragma unroll
  for (int p=0;p<2;p++){
    f32x4 v = *reinterpret_cast<const f32x4*>(s + p*512 + c*4);
    union { __hip_bfloat16 h[4]; s16x4 q; } u;
    #pragma unroll
    for (int j=0;j<4;j++) u.h[j] = __float2bfloat16(v[j]);
    *reinterpret_cast<s16x4*>(d + p*512 + c*4) = u.q;
  }
}

// ---------------- transpose W [E][R][C] -> bf16 [E][C][R], 64x64 tiles ----------------
template<int R, int C>
__global__ __launch_bounds__(256) void k_conv_t(const float* __restrict__ W,
                                                __hip_bfloat16* __restrict__ Wt){
  __shared__ float tile[64][65];
  const int e = blockIdx.z;
  const int r0 = blockIdx.y*64, c0 = blockIdx.x*64;
  const int t = threadIdx.x;
  const int tx = t & 15, ty = t >> 4;
  const float* src = W + (size_t)e*R*C;
  __hip_bfloat16* dst = Wt + (size_t)e*R*C;
  #pragma unroll
  for (int p=0;p<4;p++){
    f32x4 v = *reinterpret_cast<const f32x4*>(&src[(size_t)(r0+ty+p*16)*C + c0 + tx*4]);
    #pragma unroll
    for (int j=0;j<4;j++) tile[ty+p*16][tx*4+j] = v[j];
  }
  __syncthreads();
  const int cx = t & 7, cy = t >> 3;
  #pragma unroll
  for (int p=0;p<2;p++){
    int c = cy + p*32;
    union { __hip_bfloat16 h[8]; s16x8 s; } u;
    #pragma unroll
    for (int j=0;j<8;j++) u.h[j] = __float2bfloat16(tile[cx*8+j][c]);
    *reinterpret_cast<s16x8*>(&dst[(size_t)(c0+c)*R + r0 + cx*8]) = u.s;
  }
}

// ---------------- grouped expert GEMM (MFMA bf16), contiguous packed A ----------------
template<int K, int N, int BM, bool RELU_OUT>
__global__ __launch_bounds__(256) void k_egemm(const __hip_bfloat16* __restrict__ Asrc,
                                               const __hip_bfloat16* __restrict__ Bt,
                                               const float* __restrict__ bias,
                                               const int* __restrict__ cnt,
                                               const int* __restrict__ offs,
                                               void* __restrict__ Out){
  constexpr int WM = BM/64;
  constexpr int WN = 4/WM;
  constexpr int CW = 128/WN;
  constexpr int NF = CW/16;
  const int e = blockIdx.z;
  const int mcnt = cnt[e];
  const int mt = blockIdx.y;
  if (mt*BM >= mcnt) return;
  const int n0 = blockIdx.x*128;
  const int row0 = offs[e] + mt*BM;
  __shared__ __hip_bfloat16 Al[2][BM][32] __attribute__((aligned(16)));
  __shared__ __hip_bfloat16 Bl[2][128][32] __attribute__((aligned(16)));
  const int t = threadIdx.x, lane = t&63, wid = t>>6;
  const int rr = t>>2, kq = t&3;
  const __hip_bfloat16* a0 = Asrc + (size_t)(row0 + rr)*K + kq*8;
  const __hip_bfloat16* Bte = Bt + ((size_t)e*N + n0)*K;
  const __hip_bfloat16* b0 = Bte + (size_t)rr*K + kq*8;
  const __hip_bfloat16* b1 = Bte + (size_t)(64+rr)*K + kq*8;

  const int wm = (WM==2) ? (wid>>1) : 0;
  const int wn = (WM==2) ? (wid&1)  : wid;
  f32x4 acc[4][NF];
  #pragma unroll
  for (int i=0;i<4;i++)
    #pragma unroll
    for (int j=0;j<NF;j++){ f32x4 z = {0.f,0.f,0.f,0.f}; acc[i][j]=z; }

  auto stage = [&](int buf, int k0){
    char* Ad = (char*)(&Al[buf][0][0]) + (wid<<10);
    char* Bd = (char*)(&Bl[buf][0][0]) + (wid<<10);
    gld_lds16(a0 + k0, Ad);
    if constexpr (BM==128) gld_lds16(a0 + (size_t)64*K + k0, Ad + 4096);
    gld_lds16(b0 + k0, Bd);
    gld_lds16(b1 + k0, Bd + 4096);
  };

  stage(0, 0);
  __syncthreads();
  const int NKS = K/32;
  for (int ks=0; ks<NKS; ++ks){
    const int buf = ks & 1;
    if (ks+1 < NKS) stage(buf^1, (ks+1)*32);
    const __hip_bfloat16* Ab = &Al[buf][0][0];
    const __hip_bfloat16* Bb = &Bl[buf][0][0];
    const int rb = (lane&15), kb = (lane>>4)*8;
    s16x8 af[4], bfv[NF];
    #pragma unroll
    for (int mi=0;mi<4;mi++)
      af[mi] = *reinterpret_cast<const s16x8*>(Ab + (size_t)(wm*64 + mi*16 + rb)*32 + kb);
    #pragma unroll
    for (int ni=0;ni<NF;ni++)
      bfv[ni] = *reinterpret_cast<const s16x8*>(Bb + (size_t)(wn*CW + ni*16 + rb)*32 + kb);
    #pragma unroll
    for (int mi=0;mi<4;mi++)
      #pragma unroll
      for (int ni=0;ni<NF;ni++)
        acc[mi][ni] = __builtin_amdgcn_mfma_f32_16x16x32_bf16(af[mi], bfv[ni], acc[mi][ni], 0, 0, 0);
    __syncthreads();
  }

  const int nb = wn*CW + (lane&15);
  const int mb = wm*64 + (lane>>4)*4;
  float brg[NF];
  #pragma unroll
  for (int ni=0;ni<NF;ni++) brg[ni] = bias[e*N + n0 + nb + ni*16];
  #pragma unroll
  for (int mi=0;mi<4;mi++){
    #pragma unroll
    for (int j=0;j<4;j++){
      int m = mt*BM + mb + mi*16 + j;
      if (m < mcnt){
        size_t orow = (size_t)(row0 + mb + mi*16 + j)*N;
        #pragma unroll
        for (int ni=0;ni<NF;ni++){
          float v = acc[mi][ni][j] + brg[ni];
          if (RELU_OUT)
            ((__hip_bfloat16*)Out)[orow + n0 + nb + ni*16] = __float2bfloat16(fmaxf(v, 0.f));
          else
            ((float*)Out)[orow + n0 + nb + ni*16] = v;
        }
      }
    }
  }
}

// ---------------- combine ----------------
__global__ __launch_bounds__(256) void k_combine(const float* __restrict__ outbuf,
    const int* __restrict__ tok_row, const float* __restrict__ tok_gate,
    float* __restrict__ out){
  const int t = threadIdx.x, lane = t&63, wid = t>>6;
  const int b = blockIdx.x*4 + wid;
  const float g0 = tok_gate[b*2], g1 = tok_gate[b*2+1];
  const float* r0 = outbuf + (size_t)tok_row[b*2]*NC;
  const float* r1 = outbuf + (size_t)tok_row[b*2+1]*NC;
  float v0[8], v1[8], m0=-INFINITY, m1=-INFINITY;
  #pragma unroll
  for (int i=0;i<8;i++){
    v0[i] = r0[i*64+lane]; m0 = fmaxf(m0, v0[i]);
    v1[i] = r1[i*64+lane]; m1 = fmaxf(m1, v1[i]);
  }
  #pragma unroll
  for (int s=32;s;s>>=1){ m0 = fmaxf(m0, __shfl_xor(m0,s,64)); m1 = fmaxf(m1, __shfl_xor(m1,s,64)); }
  float s0=0.f, s1=0.f;
  #pragma unroll
  for (int i=0;i<8;i++){ s0 += expf(v0[i]-m0); s1 += expf(v1[i]-m1); }
  #pragma unroll
  for (int s=32;s;s>>=1){ s0 += __shfl_xor(s0,s,64); s1 += __shfl_xor(s1,s,64); }
  const float l0 = logf(s0)+m0, l1 = logf(s1)+m1;
  #pragma unroll
  for (int i=0;i<8;i++){
    float c = g0*expf(v0[i]-l0) + g1*expf(v1[i]-l1);
    if (c == 0.f) c = 2.2204460492503131e-16f;
    out[(size_t)b*NC + i*64+lane] = logf(c);
  }
}

extern "C" void kernel_launch(void* const* d_in, const int* in_sizes, int n_in,
                              void* d_out, int out_size, void* d_ws, size_t ws_size,
                              hipStream_t stream){
  const float* x   = (const float*)d_in[0];
  const float* x2  = (const float*)d_in[1];
  const float* Wg1 = (const float*)d_in[2];
  const float* bg1 = (const float*)d_in[3];
  const float* Wg2 = (const float*)d_in[4];
  const float* bg2 = (const float*)d_in[5];
  const float* W1  = (const float*)d_in[6];
  const float* b1  = (const float*)d_in[7];
  const float* W2  = (const float*)d_in[8];
  const float* b2  = (const float*)d_in[9];
  float* out = (float*)d_out;

  char* p = (char*)d_ws;
  size_t o = 0;
  auto take = [&](size_t bytes)->char*{ char* r = p + o; o = (o + bytes + 255) & ~(size_t)255; return r; };
  int*   cnt      = (int*)  take(32);
  int*   offs     = (int*)  take(32);
  int*   tok_e    = (int*)  take((size_t)NB*2*4);
  int*   tok_row  = (int*)  take((size_t)NB*2*4);
  float* tok_gate = (float*)take((size_t)NB*2*4);
  int*   tlist    = (int*)  take((size_t)NB*2*4);
  float* hg       = (float*)take((size_t)NB*NHG*4);
  __hip_bfloat16* Ap   = (__hip_bfloat16*)take((size_t)(NB*2+128)*KDI*2);
  __hip_bfloat16* W1t  = (__hip_bfloat16*)take((size_t)NE*NH*KDI*2);
  __hip_bfloat16* W2t  = (__hip_bfloat16*)take((size_t)NE*NC*NH*2);
  __hip_bfloat16* hbuf = (__hip_bfloat16*)take((size_t)(NB*2+128)*NH*2);
  float* outbuf   = (float*)take((size_t)NB*2*NC*4);
  __hip_bfloat16* xh   = (__hip_bfloat16*)take((size_t)NB*KDG*2);
  __hip_bfloat16* xl   = (__hip_bfloat16*)take((size_t)NB*KDG*2);
  __hip_bfloat16* wgth = (__hip_bfloat16*)take((size_t)NHG*KDG*2);
  __hip_bfloat16* wgtl = (__hip_bfloat16*)take((size_t)NHG*KDG*2);

  k_split_x<<<dim3((NB*KDG)/(256*4)), 256, 0, stream>>>(x, xh, xl);
  k_split_wt<<<dim3(NHG/64, KDG/64), 256, 0, stream>>>(Wg1, wgth, wgtl);
  k_conv_t<KDI, NH><<<dim3(NH/64, KDI/64, NE), 256, 0, stream>>>(W1, W1t);
  k_conv_t<NH, NC><<<dim3(NC/64, NH/64, NE), 256, 0, stream>>>(W2, W2t);
  k_gate_mm<<<dim3(NHG/64, NB/128), 256, 0, stream>>>(xh, xl, wgth, wgtl, bg1, hg);
  k_topk<<<dim3(NB/4), 256, 0, stream>>>(hg, Wg2, bg2, tok_e, tok_gate);
  k_dispatch<<<1, 1024, 0, stream>>>(tok_e, tok_gate, cnt, offs, tlist, tok_row, out + (size_t)NB*NC);
  k_pack<<<dim3(NB*2/2), 256, 0, stream>>>(x2, tlist, Ap);
  k_egemm<KDI, NH, 128, true ><<<dim3(NH/128, NB/128, NE), 256, 0, stream>>>(Ap, W1t, b1, cnt, offs, hbuf);
  k_egemm<NH,  NC, 64,  false><<<dim3(NC/128, NB/64, NE), 256, 0, stream>>>(hbuf, W2t, b2, cnt, offs, outbuf);
  k_combine<<<dim3(NB/4), 256, 0, stream>>>(outbuf, tok_row, tok_gate, out);
}

// Round 8
// 362.953 us; speedup vs baseline: 1.0894x; 1.0894x over previous
//
#include <hip/hip_runtime.h>
#include <hip/hip_bf16.h>
#include <math.h>

#define NE 8
#define KDG 1024
#define KDI 1024
#define NHG 512
#define NH 2048
#define NC 512
#define NB 4096

typedef float f32x4 __attribute__((ext_vector_type(4)));
typedef short s16x8 __attribute__((ext_vector_type(8)));
typedef short s16x4 __attribute__((ext_vector_type(4)));

__device__ __forceinline__ void gld_lds16(const void* g, void* l){
  __builtin_amdgcn_global_load_lds((const __attribute__((address_space(1))) void*)g,
                                   (__attribute__((address_space(3))) void*)l, 16, 0, 0);
}

// ---------------- fused prep: all fp32->bf16 converts/transposes in ONE launch ----------------
// block ranges:
//  [0,4096):      W1 [E][1024][2048] -> W1t [E][2048][1024]   (64x64 tiles, 512/expert)
//  [4096,6144):   W2 [E][2048][512]  -> W2t [E][512][2048]    (256/expert)
//  [6144,8192):   split x -> xh, xl          (2048 elems/block)
//  [8192,10240):  x2 -> x2b bf16             (2048 elems/block)
//  [10240,10368): Wg1 [1024][512] -> wgth/wgtl [512][1024]    (hi/lo transpose)
__device__ __forceinline__ void trans64(const float* __restrict__ src, int C, int R,
                                        __hip_bfloat16* __restrict__ dh,
                                        __hip_bfloat16* __restrict__ dl,
                                        int r0, int c0, int t, float (&tile)[64][65]){
  const int tx = t & 15, ty = t >> 4;
  #pragma unroll
  for (int p=0;p<4;p++){
    f32x4 v = *reinterpret_cast<const f32x4*>(&src[(size_t)(r0+ty+p*16)*C + c0 + tx*4]);
    #pragma unroll
    for (int j=0;j<4;j++) tile[ty+p*16][tx*4+j] = v[j];
  }
  __syncthreads();
  const int cx = t & 7, cy = t >> 3;
  #pragma unroll
  for (int p=0;p<2;p++){
    int c = cy + p*32;
    union { __hip_bfloat16 h[8]; s16x8 s; } uh, ul;
    #pragma unroll
    for (int j=0;j<8;j++){
      float v = tile[cx*8+j][c];
      uh.h[j] = __float2bfloat16(v);
      if (dl) ul.h[j] = __float2bfloat16(v - __bfloat162float(uh.h[j]));
    }
    *reinterpret_cast<s16x8*>(&dh[(size_t)(c0+c)*R + r0 + cx*8]) = uh.s;
    if (dl) *reinterpret_cast<s16x8*>(&dl[(size_t)(c0+c)*R + r0 + cx*8]) = ul.s;
  }
}

__device__ __forceinline__ void conv8(const float* __restrict__ in,
                                      __hip_bfloat16* __restrict__ oh,
                                      __hip_bfloat16* __restrict__ ol,
                                      size_t base){
  f32x4 v0 = *reinterpret_cast<const f32x4*>(in + base);
  f32x4 v1 = *reinterpret_cast<const f32x4*>(in + base + 4);
  union { __hip_bfloat16 h[8]; s16x8 s; } uh, ul;
  #pragma unroll
  for (int j=0;j<4;j++){
    uh.h[j]   = __float2bfloat16(v0[j]);
    uh.h[j+4] = __float2bfloat16(v1[j]);
    if (ol){
      ul.h[j]   = __float2bfloat16(v0[j] - __bfloat162float(uh.h[j]));
      ul.h[j+4] = __float2bfloat16(v1[j] - __bfloat162float(uh.h[j+4]));
    }
  }
  *reinterpret_cast<s16x8*>(oh + base) = uh.s;
  if (ol) *reinterpret_cast<s16x8*>(ol + base) = ul.s;
}

__global__ __launch_bounds__(256) void k_prep(const float* __restrict__ x,
                                              const float* __restrict__ x2,
                                              const float* __restrict__ Wg1,
                                              const float* __restrict__ W1,
                                              const float* __restrict__ W2,
                                              __hip_bfloat16* __restrict__ xh,
                                              __hip_bfloat16* __restrict__ xl,
                                              __hip_bfloat16* __restrict__ x2b,
                                              __hip_bfloat16* __restrict__ wgth,
                                              __hip_bfloat16* __restrict__ wgtl,
                                              __hip_bfloat16* __restrict__ W1t,
                                              __hip_bfloat16* __restrict__ W2t){
  __shared__ float tile[64][65];
  const int bid = blockIdx.x, t = threadIdx.x;
  if (bid < 4096){
    int e = bid >> 9, rem = bid & 511;
    int rt = rem >> 5, ct = rem & 31;
    trans64(W1 + (size_t)e*KDI*NH, NH, KDI, W1t + (size_t)e*NH*KDI, nullptr,
            rt*64, ct*64, t, tile);
  } else if (bid < 6144){
    int b = bid - 4096;
    int e = b >> 8, rem = b & 255;
    int rt = rem >> 3, ct = rem & 7;
    trans64(W2 + (size_t)e*NH*NC, NC, NH, W2t + (size_t)e*NC*NH, nullptr,
            rt*64, ct*64, t, tile);
  } else if (bid < 8192){
    size_t base = ((size_t)(bid - 6144)*256 + t)*8;
    conv8(x, xh, xl, base);
  } else if (bid < 10240){
    size_t base = ((size_t)(bid - 8192)*256 + t)*8;
    conv8(x2, x2b, nullptr, base);
  } else {
    int rem = bid - 10240;
    int rt = rem >> 3, ct = rem & 7;
    trans64(Wg1, NHG, KDG, wgth, wgtl, rt*64, ct*64, t, tile);
  }
}

// ---------------- gating GEMM1 via hi/lo bf16 MFMA (64x64 tile) ----------------
__global__ __launch_bounds__(256) void k_gate_mm(const __hip_bfloat16* __restrict__ xh,
                                                 const __hip_bfloat16* __restrict__ xl,
                                                 const __hip_bfloat16* __restrict__ wh,
                                                 const __hip_bfloat16* __restrict__ wl,
                                                 const float* __restrict__ bg1,
                                                 float* __restrict__ hg){
  __shared__ __hip_bfloat16 Ah[2][64][32] __attribute__((aligned(16)));
  __shared__ __hip_bfloat16 Ax[2][64][32] __attribute__((aligned(16)));
  __shared__ __hip_bfloat16 Bh[2][64][32] __attribute__((aligned(16)));
  __shared__ __hip_bfloat16 Bx[2][64][32] __attribute__((aligned(16)));
  const int m0 = blockIdx.y*64, n0 = blockIdx.x*64;
  const int t = threadIdx.x, lane = t&63, wid = t>>6;
  const int rr = t>>2, kq = t&3;
  const __hip_bfloat16* pah = xh + (size_t)(m0+rr)*KDG + kq*8;
  const __hip_bfloat16* pax = xl + (size_t)(m0+rr)*KDG + kq*8;
  const __hip_bfloat16* pbh = wh + (size_t)(n0+rr)*KDG + kq*8;
  const __hip_bfloat16* pbx = wl + (size_t)(n0+rr)*KDG + kq*8;

  const int wm = wid>>1, wn = wid&1;
  f32x4 acc[2][2];
  #pragma unroll
  for (int i=0;i<2;i++)
    #pragma unroll
    for (int j=0;j<2;j++){ f32x4 z={0.f,0.f,0.f,0.f}; acc[i][j]=z; }

  auto stage = [&](int buf, int k0){
    size_t wo = (size_t)(wid<<10);
    gld_lds16(pah + k0, (char*)(&Ah[buf][0][0]) + wo);
    gld_lds16(pax + k0, (char*)(&Ax[buf][0][0]) + wo);
    gld_lds16(pbh + k0, (char*)(&Bh[buf][0][0]) + wo);
    gld_lds16(pbx + k0, (char*)(&Bx[buf][0][0]) + wo);
  };

  stage(0, 0);
  __syncthreads();
  for (int ks=0; ks<KDG/32; ++ks){
    const int buf = ks & 1;
    if (ks+1 < KDG/32) stage(buf^1, (ks+1)*32);
    const int rb = lane&15, kb = (lane>>4)*8;
    s16x8 ah[2], ax[2], bh[2], bx[2];
    #pragma unroll
    for (int mi=0;mi<2;mi++){
      ah[mi] = *reinterpret_cast<const s16x8*>(&Ah[buf][wm*32+mi*16+rb][kb]);
      ax[mi] = *reinterpret_cast<const s16x8*>(&Ax[buf][wm*32+mi*16+rb][kb]);
    }
    #pragma unroll
    for (int ni=0;ni<2;ni++){
      bh[ni] = *reinterpret_cast<const s16x8*>(&Bh[buf][wn*32+ni*16+rb][kb]);
      bx[ni] = *reinterpret_cast<const s16x8*>(&Bx[buf][wn*32+ni*16+rb][kb]);
    }
    #pragma unroll
    for (int mi=0;mi<2;mi++)
      #pragma unroll
      for (int ni=0;ni<2;ni++){
        acc[mi][ni] = __builtin_amdgcn_mfma_f32_16x16x32_bf16(ah[mi], bh[ni], acc[mi][ni], 0,0,0);
        acc[mi][ni] = __builtin_amdgcn_mfma_f32_16x16x32_bf16(ah[mi], bx[ni], acc[mi][ni], 0,0,0);
        acc[mi][ni] = __builtin_amdgcn_mfma_f32_16x16x32_bf16(ax[mi], bh[ni], acc[mi][ni], 0,0,0);
      }
    __syncthreads();
  }
  #pragma unroll
  for (int mi=0;mi<2;mi++){
    #pragma unroll
    for (int j=0;j<4;j++){
      int row = m0 + wm*32 + mi*16 + (lane>>4)*4 + j;
      #pragma unroll
      for (int ni=0;ni<2;ni++){
        int col = n0 + wn*32 + ni*16 + (lane&15);
        hg[(size_t)row*NHG + col] = fmaxf(acc[mi][ni][j] + bg1[col], 0.f);
      }
    }
  }
}

// ---------------- top-2 per token ----------------
__global__ __launch_bounds__(256) void k_topk(const float* __restrict__ hg,
                                              const float* __restrict__ Wg2,
                                              const float* __restrict__ bg2,
                                              int* __restrict__ tok_e,
                                              float* __restrict__ tok_gate){
  __shared__ float w[NE][NHG];
  const int t = threadIdx.x;
  for (int i=t; i<NE*NHG; i+=256){ int k=i>>3, e=i&7; w[e][k] = Wg2[i]; }
  __syncthreads();
  const int lane = t & 63, wid = t >> 6;
  const int b = blockIdx.x*4 + wid;
  float acc[NE];
  #pragma unroll
  for (int e=0;e<NE;e++) acc[e]=0.f;
  #pragma unroll
  for (int j=0;j<8;j++){
    float hv = hg[(size_t)b*NHG + j*64 + lane];
    #pragma unroll
    for (int e=0;e<NE;e++) acc[e] += hv * w[e][j*64+lane];
  }
  #pragma unroll
  for (int e=0;e<NE;e++){
    float v = acc[e];
    #pragma unroll
    for (int s=32;s;s>>=1) v += __shfl_xor(v, s, 64);
    acc[e] = v;
  }
  if (lane==0){
    float lg[NE];
    #pragma unroll
    for (int e=0;e<NE;e++) lg[e] = acc[e] + bg2[e];
    int i1=0;
    #pragma unroll
    for (int e=1;e<NE;e++) if (lg[e] > lg[i1]) i1=e;
    int i2 = (i1==0)?1:0;
    #pragma unroll
    for (int e=0;e<NE;e++){ if (e==i1 || e==i2) continue; if (lg[e] > lg[i2]) i2=e; }
    float pr = expf((lg[i2]-lg[i1])*0.2f);
    float s  = 1.f + pr;
    tok_e[b*2]=i1;      tok_e[b*2+1]=i2;
    tok_gate[b*2]=1.f/s; tok_gate[b*2+1]=pr/s;
  }
}

// ---------------- dispatcher build: ONE block, LDS atomics only ----------------
__global__ __launch_bounds__(1024) void k_dispatch(const int* __restrict__ tok_e,
                                                   const float* __restrict__ tok_gate,
                                                   int* __restrict__ cnt, int* __restrict__ offs,
                                                   int* __restrict__ tlist, int* __restrict__ tok_row,
                                                   float* __restrict__ loss_out){
  __shared__ int lcnt[NE];
  __shared__ float limp[NE];
  __shared__ int loffs[NE];
  const int t = threadIdx.x;
  if (t < NE){ lcnt[t]=0; limp[t]=0.f; }
  __syncthreads();
  int e[8], p[8];
  #pragma unroll
  for (int j=0;j<8;j++){
    int i = t*8+j;
    e[j] = tok_e[i];
    p[j] = atomicAdd(&lcnt[e[j]], 1);
    atomicAdd(&limp[e[j]], tok_gate[i]);
  }
  __syncthreads();
  if (t==0){
    int o=0; float si=0.f, sl=0.f;
    for (int k=0;k<NE;k++){ loffs[k]=o; o+=lcnt[k]; si+=limp[k]; sl+=(float)lcnt[k]; }
    float mi=si/NE, ml=sl/NE, vi=0.f, vl=0.f;
    for (int k=0;k<NE;k++){ float d=limp[k]-mi; vi+=d*d; float dl=(float)lcnt[k]-ml; vl+=dl*dl; }
    vi/=(NE-1); vl/=(NE-1);
    loss_out[0] = (vi/(mi*mi+1e-10f) + vl/(ml*ml+1e-10f)) * 0.01f;
  }
  __syncthreads();
  if (t < NE){ cnt[t]=lcnt[t]; offs[t]=loffs[t]; }
  #pragma unroll
  for (int j=0;j<8;j++){
    int i = t*8+j;
    int row = loffs[e[j]] + p[j];
    tok_row[i] = row;
    tlist[row] = i>>1;
  }
}

// ---------------- grouped expert GEMM (MFMA bf16), BN=128, BM in {64,128} ----------------
template<int K, int N, int BM, bool GATHER, bool RELU_OUT>
__global__ __launch_bounds__(256) void k_egemm(const __hip_bfloat16* __restrict__ Asrc,
                                               const __hip_bfloat16* __restrict__ Bt,
                                               const float* __restrict__ bias,
                                               const int* __restrict__ cnt,
                                               const int* __restrict__ offs,
                                               const int* __restrict__ tlist,
                                               void* __restrict__ Out){
  constexpr int WM = BM/64;
  constexpr int WN = 4/WM;
  constexpr int CW = 128/WN;
  constexpr int NF = CW/16;
  const int e = blockIdx.z;
  const int mcnt = cnt[e];
  const int mt = blockIdx.y;
  if (mt*BM >= mcnt) return;
  const int n0 = blockIdx.x*128;
  const int offs_e = offs[e];
  __shared__ __hip_bfloat16 Al[2][BM][32] __attribute__((aligned(16)));
  __shared__ __hip_bfloat16 Bl[2][128][32] __attribute__((aligned(16)));
  __shared__ int tk[BM];
  const int t = threadIdx.x, lane = t&63, wid = t>>6;
  for (int i=t;i<BM;i+=256){
    int m = mt*BM + i;
    int ml = m < mcnt ? m : (mcnt-1);
    tk[i] = GATHER ? tlist[offs_e + ml] : (offs_e + ml);
  }
  __syncthreads();
  const int rr = t>>2, kq = t&3;
  const __hip_bfloat16* a0 = Asrc + (size_t)tk[rr]*K + kq*8;
  const __hip_bfloat16* a1 = nullptr;
  if constexpr (BM==128) a1 = Asrc + (size_t)tk[64+rr]*K + kq*8;
  const __hip_bfloat16* Bte = Bt + ((size_t)e*N + n0)*K;
  const __hip_bfloat16* b0 = Bte + (size_t)rr*K + kq*8;
  const __hip_bfloat16* b1 = Bte + (size_t)(64+rr)*K + kq*8;

  const int wm = (WM==2) ? (wid>>1) : 0;
  const int wn = (WM==2) ? (wid&1)  : wid;
  f32x4 acc[4][NF];
  #pragma unroll
  for (int i=0;i<4;i++)
    #pragma unroll
    for (int j=0;j<NF;j++){ f32x4 z = {0.f,0.f,0.f,0.f}; acc[i][j]=z; }

  auto stage = [&](int buf, int k0){
    char* Ad = (char*)(&Al[buf][0][0]) + (wid<<10);
    char* Bd = (char*)(&Bl[buf][0][0]) + (wid<<10);
    gld_lds16(a0 + k0, Ad);
    if constexpr (BM==128) gld_lds16(a1 + k0, Ad + 4096);
    gld_lds16(b0 + k0, Bd);
    gld_lds16(b1 + k0, Bd + 4096);
  };

  stage(0, 0);
  __syncthreads();
  const int NKS = K/32;
  for (int ks=0; ks<NKS; ++ks){
    const int buf = ks & 1;
    if (ks+1 < NKS) stage(buf^1, (ks+1)*32);
    const __hip_bfloat16* Ab = &Al[buf][0][0];
    const __hip_bfloat16* Bb = &Bl[buf][0][0];
    const int rb = (lane&15), kb = (lane>>4)*8;
    s16x8 af[4], bfv[NF];
    #pragma unroll
    for (int mi=0;mi<4;mi++)
      af[mi] = *reinterpret_cast<const s16x8*>(Ab + (size_t)(wm*64 + mi*16 + rb)*32 + kb);
    #pragma unroll
    for (int ni=0;ni<NF;ni++)
      bfv[ni] = *reinterpret_cast<const s16x8*>(Bb + (size_t)(wn*CW + ni*16 + rb)*32 + kb);
    #pragma unroll
    for (int mi=0;mi<4;mi++)
      #pragma unroll
      for (int ni=0;ni<NF;ni++)
        acc[mi][ni] = __builtin_amdgcn_mfma_f32_16x16x32_bf16(af[mi], bfv[ni], acc[mi][ni], 0, 0, 0);
    __syncthreads();
  }

  const int nb = wn*CW + (lane&15);
  const int mb = wm*64 + (lane>>4)*4;
  float brg[NF];
  #pragma unroll
  for (int ni=0;ni<NF;ni++) brg[ni] = bias[e*N + n0 + nb + ni*16];
  #pragma unroll
  for (int mi=0;mi<4;mi++){
    #pragma unroll
    for (int j=0;j<4;j++){
      int m = mt*BM + mb + mi*16 + j;
      if (m < mcnt){
        size_t orow = (size_t)(offs_e + m)*N;
        #pragma unroll
        for (int ni=0;ni<NF;ni++){
          float v = acc[mi][ni][j] + brg[ni];
          if (RELU_OUT)
            ((__hip_bfloat16*)Out)[orow + n0 + nb + ni*16] = __float2bfloat16(fmaxf(v, 0.f));
          else
            ((float*)Out)[orow + n0 + nb + ni*16] = v;
        }
      }
    }
  }
}

// ---------------- combine ----------------
__global__ __launch_bounds__(256) void k_combine(const float* __restrict__ outbuf,
    const int* __restrict__ tok_row, const float* __restrict__ tok_gate,
    float* __restrict__ out){
  const int t = threadIdx.x, lane = t&63, wid = t>>6;
  const int b = blockIdx.x*4 + wid;
  const float g0 = tok_gate[b*2], g1 = tok_gate[b*2+1];
  const float* r0 = outbuf + (size_t)tok_row[b*2]*NC;
  const float* r1 = outbuf + (size_t)tok_row[b*2+1]*NC;
  float v0[8], v1[8], m0=-INFINITY, m1=-INFINITY;
  #pragma unroll
  for (int i=0;i<8;i++){
    v0[i] = r0[i*64+lane]; m0 = fmaxf(m0, v0[i]);
    v1[i] = r1[i*64+lane]; m1 = fmaxf(m1, v1[i]);
  }
  #pragma unroll
  for (int s=32;s;s>>=1){ m0 = fmaxf(m0, __shfl_xor(m0,s,64)); m1 = fmaxf(m1, __shfl_xor(m1,s,64)); }
  float s0=0.f, s1=0.f;
  #pragma unroll
  for (int i=0;i<8;i++){ s0 += expf(v0[i]-m0); s1 += expf(v1[i]-m1); }
  #pragma unroll
  for (int s=32;s;s>>=1){ s0 += __shfl_xor(s0,s,64); s1 += __shfl_xor(s1,s,64); }
  const float l0 = logf(s0)+m0, l1 = logf(s1)+m1;
  #pragma unroll
  for (int i=0;i<8;i++){
    float c = g0*expf(v0[i]-l0) + g1*expf(v1[i]-l1);
    if (c == 0.f) c = 2.2204460492503131e-16f;
    out[(size_t)b*NC + i*64+lane] = logf(c);
  }
}

extern "C" void kernel_launch(void* const* d_in, const int* in_sizes, int n_in,
                              void* d_out, int out_size, void* d_ws, size_t ws_size,
                              hipStream_t stream){
  const float* x   = (const float*)d_in[0];
  const float* x2  = (const float*)d_in[1];
  const float* Wg1 = (const float*)d_in[2];
  const float* bg1 = (const float*)d_in[3];
  const float* Wg2 = (const float*)d_in[4];
  const float* bg2 = (const float*)d_in[5];
  const float* W1  = (const float*)d_in[6];
  const float* b1  = (const float*)d_in[7];
  const float* W2  = (const float*)d_in[8];
  const float* b2  = (const float*)d_in[9];
  float* out = (float*)d_out;

  char* p = (char*)d_ws;
  size_t o = 0;
  auto take = [&](size_t bytes)->char*{ char* r = p + o; o = (o + bytes + 255) & ~(size_t)255; return r; };
  int*   cnt      = (int*)  take(32);
  int*   offs     = (int*)  take(32);
  int*   tok_e    = (int*)  take((size_t)NB*2*4);
  int*   tok_row  = (int*)  take((size_t)NB*2*4);
  float* tok_gate = (float*)take((size_t)NB*2*4);
  int*   tlist    = (int*)  take((size_t)NB*2*4);
  float* hg       = (float*)take((size_t)NB*NHG*4);
  __hip_bfloat16* x2b  = (__hip_bfloat16*)take((size_t)NB*KDI*2);
  __hip_bfloat16* W1t  = (__hip_bfloat16*)take((size_t)NE*NH*KDI*2);
  __hip_bfloat16* W2t  = (__hip_bfloat16*)take((size_t)NE*NC*NH*2);
  __hip_bfloat16* hbuf = (__hip_bfloat16*)take((size_t)NB*2*NH*2);
  float* outbuf   = (float*)take((size_t)NB*2*NC*4);
  __hip_bfloat16* xh   = (__hip_bfloat16*)take((size_t)NB*KDG*2);
  __hip_bfloat16* xl   = (__hip_bfloat16*)take((size_t)NB*KDG*2);
  __hip_bfloat16* wgth = (__hip_bfloat16*)take((size_t)NHG*KDG*2);
  __hip_bfloat16* wgtl = (__hip_bfloat16*)take((size_t)NHG*KDG*2);

  k_prep<<<dim3(10368), 256, 0, stream>>>(x, x2, Wg1, W1, W2, xh, xl, x2b, wgth, wgtl, W1t, W2t);
  k_gate_mm<<<dim3(NHG/64, NB/64), 256, 0, stream>>>(xh, xl, wgth, wgtl, bg1, hg);
  k_topk<<<dim3(NB/4), 256, 0, stream>>>(hg, Wg2, bg2, tok_e, tok_gate);
  k_dispatch<<<1, 1024, 0, stream>>>(tok_e, tok_gate, cnt, offs, tlist, tok_row, out + (size_t)NB*NC);
  k_egemm<KDI, NH, 128, true,  true ><<<dim3(NH/128, NB/128, NE), 256, 0, stream>>>(x2b, W1t, b1, cnt, offs, tlist, hbuf);
  k_egemm<NH,  NC, 64,  false, false><<<dim3(NC/128, NB/64, NE), 256, 0, stream>>>(hbuf, W2t, b2, cnt, offs, tlist, outbuf);
  k_combine<<<dim3(NB/4), 256, 0, stream>>>(outbuf, tok_row, tok_gate, out);
}